// Round 2
// baseline (104.586 us; speedup 1.0000x reference)
//
#include <hip/hip_runtime.h>

#define K_DIM 131072
#define NROW 256
#define BK 64
#define TPB 1024
#define TEMP 14.285714285714286f

typedef float f32x4  __attribute__((ext_vector_type(4)));
typedef float f32x16 __attribute__((ext_vector_type(16)));
typedef short s16x8  __attribute__((ext_vector_type(8)));

// fp32 -> bf16 round-to-nearest-even, packed pair into one u32
__device__ __forceinline__ unsigned int pack2bf(float a, float b) {
    unsigned int ua = __float_as_uint(a);
    ua = (ua + 0x7FFFu + ((ua >> 16) & 1u)) >> 16;
    unsigned int ub = __float_as_uint(b);
    ub = (ub + 0x7FFFu + ((ub >> 16) & 1u)) & 0xFFFF0000u;
    return ua | ub;
}

// Stage 1: split-K GEMM over C-quarters.
// grid = 4*split blocks of 1024 threads (16 waves of 32x32 MFMA tiles).
// Block g -> (k-chunk, quarter) with all 4 quarters of a k-chunk on the same
// XCD (g%8 == k%8) so A/B panel re-reads hit that XCD's L2.
// LDS 64 KB (2 bufs x (A 16KB + B 16KB)) -> 2 blocks/CU. acc=16, prefetch=32 VGPR.
__global__ __launch_bounds__(TPB, 4) void gemm_q(
    const float* __restrict__ A, const float* __restrict__ Bm,
    float* __restrict__ partials, int KC)
{
    __shared__ __align__(16) unsigned short As[2][128 * BK];  // 16 KB each
    __shared__ __align__(16) unsigned short Bs[2][128 * BK];

    const int g    = blockIdx.x;
    const int k    = (g & 7) | ((g >> 5) << 3);   // k-chunk id
    const int q    = (g >> 3) & 3;                // quarter id
    const int qrow = (q >> 1) * 128;
    const int qcol = (q & 1) * 128;

    const int t    = threadIdx.x;
    const int lane = t & 63;
    const int w    = t >> 6;          // 0..15
    const int wm   = (w >> 2) * 32;   // wave row base within quarter
    const int wn   = (w & 3) * 32;    // wave col base within quarter

    // staging: thread -> (row = t>>4 [+64], f32 col = (t&15)*4); 256 B/row/instr
    const int srow  = t >> 4;
    const int scolb = (t & 15) * 8;   // byte col in bf16 LDS row
    const int soff0 = (srow * 128 + scolb) ^ ((srow & 7) << 4);
    const int soff1 = soff0 + 64 * 128;   // row+64: same swizzle bits

    const long k0      = (long)k * KC;
    const int  NS      = KC / BK;
    const long rowstep = 64L * K_DIM;

    const float* aP = A  + (long)(qrow + srow) * K_DIM + k0 + (t & 15) * 4;
    const float* bP = Bm + (long)(qcol + srow) * K_DIM + k0 + (t & 15) * 4;

    // fragment-read constants (32x32x16: row = lane&31, k = (lane>>5)*8 + j)
    const int arow  = wm + (lane & 31);
    const int brow  = wn + (lane & 31);
    const int abase = arow * 128;
    const int bbase = brow * 128;
    const int aswz  = (arow & 7) << 4;
    const int bswz  = (brow & 7) << 4;
    const int khalf = (lane >> 5) * 16;   // byte offset of lane's k-half

    f32x16 acc = {0.f};

    // depth-2 prefetch, static slots (no runtime-indexed reg arrays)
    f32x4 a0p0 = *(const f32x4*)(aP);
    f32x4 a0p1 = *(const f32x4*)(aP + rowstep);
    f32x4 b0p0 = *(const f32x4*)(bP);
    f32x4 b0p1 = *(const f32x4*)(bP + rowstep);
    f32x4 a1p0 = *(const f32x4*)(aP + BK);
    f32x4 a1p1 = *(const f32x4*)(aP + BK + rowstep);
    f32x4 b1p0 = *(const f32x4*)(bP + BK);
    f32x4 b1p1 = *(const f32x4*)(bP + BK + rowstep);

#define TILE_BODY(BUF, RA0, RA1, RB0, RB1, NEXT_I)                            \
    do {                                                                      \
        *(uint2*)((char*)As[BUF] + soff0) =                                   \
            make_uint2(pack2bf(RA0.x, RA0.y), pack2bf(RA0.z, RA0.w));         \
        *(uint2*)((char*)As[BUF] + soff1) =                                   \
            make_uint2(pack2bf(RA1.x, RA1.y), pack2bf(RA1.z, RA1.w));         \
        *(uint2*)((char*)Bs[BUF] + soff0) =                                   \
            make_uint2(pack2bf(RB0.x, RB0.y), pack2bf(RB0.z, RB0.w));         \
        *(uint2*)((char*)Bs[BUF] + soff1) =                                   \
            make_uint2(pack2bf(RB1.x, RB1.y), pack2bf(RB1.z, RB1.w));         \
        if ((NEXT_I) < NS) {                                                  \
            const float* ap_ = aP + (long)(NEXT_I) * BK;                      \
            const float* bp_ = bP + (long)(NEXT_I) * BK;                      \
            RA0 = *(const f32x4*)(ap_);                                       \
            RA1 = *(const f32x4*)(ap_ + rowstep);                             \
            RB0 = *(const f32x4*)(bp_);                                       \
            RB1 = *(const f32x4*)(bp_ + rowstep);                             \
        }                                                                     \
        /* drain LDS writes only; prefetch loads stay in flight */            \
        asm volatile("s_waitcnt lgkmcnt(0)\n\ts_barrier" ::: "memory");       \
        _Pragma("unroll")                                                     \
        for (int ks = 0; ks < 4; ++ks) {                                      \
            s16x8 af = *(const s16x8*)((const char*)As[BUF] +                 \
                         (abase + ((ks * 32 + khalf) ^ aswz)));               \
            s16x8 bf = *(const s16x8*)((const char*)Bs[BUF] +                 \
                         (bbase + ((ks * 32 + khalf) ^ bswz)));               \
            acc = __builtin_amdgcn_mfma_f32_32x32x16_bf16(af, bf, acc,        \
                                                          0, 0, 0);           \
        }                                                                     \
    } while (0)

    for (int i = 0; i < NS; i += 2) {
        TILE_BODY(0, a0p0, a0p1, b0p0, b0p1, i + 2);
        TILE_BODY(1, a1p0, a1p1, b1p0, b1p1, i + 3);
    }
#undef TILE_BODY

    // epilogue: C/D map col=lane&31, row=(reg&3)+8*(reg>>2)+4*(lane>>5)
    float* outp = partials + (size_t)k * (NROW * NROW);
    const int ccol  = qcol + wn + (lane & 31);
    const int rbase = qrow + wm + (lane >> 5) * 4;
#pragma unroll
    for (int r = 0; r < 16; ++r) {
        int crow = rbase + (r & 3) + 8 * (r >> 2);
        outp[(size_t)crow * NROW + ccol] = acc[r];
    }
}

// Stage 2: reduce partials over split; per-row masked exp, rowsum, pos, rowloss; store E.
__global__ __launch_bounds__(NROW) void reduce_loss_rows(
    const float* __restrict__ partials, const int* __restrict__ idx,
    float* __restrict__ E, float* __restrict__ rowloss, float* __restrict__ posbuf,
    int split)
{
    const int b = blockIdx.x;   // row
    const int t = threadIdx.x;  // col
    const float* p = partials + b * NROW + t;
    float sum = 0.f;
#pragma unroll 8
    for (int s = 0; s < split; ++s)
        sum += p[(size_t)s * (NROW * NROW)];

    const float logit = sum * TEMP;
    const bool  mask  = (idx[b] != idx[t]) || (b == t);
    const float e     = mask ? expf(logit) : 0.0f;
    E[b * NROW + t] = e;

    __shared__ float red[NROW];
    __shared__ float posv;
    if (t == b) posv = logit;
    red[t] = e;
    __syncthreads();
#pragma unroll
    for (int s = NROW / 2; s > 0; s >>= 1) {
        if (t < s) red[t] += red[t + s];
        __syncthreads();
    }
    if (t == 0) {
        posbuf[b]  = posv;
        rowloss[b] = logf(red[0]) - posv;
    }
}

// Stage 3: column sums of E, column losses, final mean.
__global__ __launch_bounds__(NROW) void finalize_loss(
    const float* __restrict__ E, const float* __restrict__ rowloss,
    const float* __restrict__ posbuf, float* __restrict__ out)
{
    const int t = threadIdx.x;
    float csum = 0.f;
#pragma unroll 8
    for (int i = 0; i < NROW; ++i)
        csum += E[i * NROW + t];
    const float closs = logf(csum) - posbuf[t];
    const float rl    = rowloss[t];

    __shared__ float redc[NROW];
    __shared__ float redr[NROW];
    redc[t] = closs;
    redr[t] = rl;
    __syncthreads();
#pragma unroll
    for (int s = NROW / 2; s > 0; s >>= 1) {
        if (t < s) { redc[t] += redc[t + s]; redr[t] += redr[t + s]; }
        __syncthreads();
    }
    if (t == 0)
        out[0] = 0.5f * (redc[0] + redr[0]) * (1.0f / (float)NROW);
}

extern "C" void kernel_launch(void* const* d_in, const int* in_sizes, int n_in,
                              void* d_out, int out_size, void* d_ws, size_t ws_size,
                              hipStream_t stream)
{
    (void)in_sizes; (void)n_in; (void)out_size;
    const float* A   = (const float*)d_in[0];
    const float* Bm  = (const float*)d_in[1];
    const int*   idx = (const int*)d_in[2];
    float*       out = (float*)d_out;

    // adaptive split-K based on workspace size (partials: split * 256KB)
    int split = 256;
    const size_t extra = (size_t)(NROW * NROW + 2 * NROW) * sizeof(float);
    while (split > 8 &&
           (size_t)split * NROW * NROW * sizeof(float) + extra > ws_size)
        split >>= 1;
    const int KC = K_DIM / split;

    float* partials = (float*)d_ws;
    float* E        = partials + (size_t)split * NROW * NROW;
    float* rowloss  = E + NROW * NROW;
    float* posbuf   = rowloss + NROW;

    gemm_q<<<split * 4, TPB, 0, stream>>>(A, Bm, partials, KC);
    reduce_loss_rows<<<NROW, NROW, 0, stream>>>(partials, idx, E, rowloss, posbuf, split);
    finalize_loss<<<1, NROW, 0, stream>>>(E, rowloss, posbuf, out);
}

// Round 3
// 99.131 us; speedup vs baseline: 1.0550x; 1.0550x over previous
//
#include <hip/hip_runtime.h>

#define K_DIM 131072
#define NROW 256
#define BK 32
#define TPB 1024
#define TEMP 14.285714285714286f

typedef float f32x4  __attribute__((ext_vector_type(4)));
typedef float f32x16 __attribute__((ext_vector_type(16)));
typedef short s16x8  __attribute__((ext_vector_type(8)));
typedef unsigned int u32;

typedef const __attribute__((address_space(1))) void gvoid;
typedef __attribute__((address_space(3))) void lvoid;

__device__ __forceinline__ u32 cvt_pk_bf16(float lo, float hi) {
    u32 r;
    asm("v_cvt_pk_bf16_f32 %0, %1, %2" : "=v"(r) : "v"(lo), "v"(hi));
    return r;
}

// read one bf16 MFMA fragment (8 k-elements) from a swizzled fp32 LDS tile
__device__ __forceinline__ s16x8 rd_frag(const float* base, int row, int sb) {
    const char* p = (const char*)base + row * 128;
    const int swz = (row & 7) << 4;
    f32x4 lo = *(const f32x4*)(p + ((sb)      ^ swz));
    f32x4 hi = *(const f32x4*)(p + ((sb + 16) ^ swz));
    union { u32 u[4]; s16x8 s; } r;
    r.u[0] = cvt_pk_bf16(lo.x, lo.y);
    r.u[1] = cvt_pk_bf16(lo.z, lo.w);
    r.u[2] = cvt_pk_bf16(hi.x, hi.y);
    r.u[3] = cvt_pk_bf16(hi.z, hi.w);
    return r.s;
}

// Stage 1: split-K GEMM, full 256x256 C per block. 16 waves (4x4), wave tile
// 64x64 (2x2 MFMA 32x32x16 quadrants). fp32 staged to LDS by global_load_lds
// (no dest regs -> no compiler vmcnt waits); counted vmcnt(4) keeps 2 tiles
// in flight at all times. fp32->bf16 on the fragment-read path.
__global__ __launch_bounds__(TPB) void gemm_fullc(
    const float* __restrict__ A, const float* __restrict__ Bm,
    float* __restrict__ partials, int KC)
{
    __shared__ __align__(16) float As[2][NROW * BK];  // 32 KB per buf
    __shared__ __align__(16) float Bs[2][NROW * BK];

    const int t    = threadIdx.x;
    const int lane = t & 63;
    const int w    = t >> 6;
    const int wm   = (w >> 2) * 64;
    const int wn   = (w & 3) * 64;

    const long k0 = (long)blockIdx.x * (long)KC;
    const int  NS = KC / BK;

    // staging: wave w owns segs {2w, 2w+1}; seg s covers rows s*8..s*8+7.
    // LDS dest is linear (HW: base + lane*16); source column-chunk is
    // pre-swizzled (chunk ^= row&7, involution) so reads can XOR the same way.
    const int  seg0      = w * 2;
    const long laneRow   = lane >> 3;                       // 0..7
    const int  laneChunk = (lane & 7) ^ (int)laneRow;       // 16B chunk
    const long laneOff   = laneRow * (long)K_DIM + (long)laneChunk * 4;

    const float* aS0 = A  + (long)(seg0 * 8)     * K_DIM + k0 + laneOff;
    const float* aS1 = A  + (long)(seg0 * 8 + 8) * K_DIM + k0 + laneOff;
    const float* bS0 = Bm + (long)(seg0 * 8)     * K_DIM + k0 + laneOff;
    const float* bS1 = Bm + (long)(seg0 * 8 + 8) * K_DIM + k0 + laneOff;

#define ISSUE(TILE, BUF)                                                      \
    do {                                                                      \
        const long o_ = (long)(TILE) * BK;                                    \
        __builtin_amdgcn_global_load_lds((gvoid*)(aS0 + o_),                  \
            (lvoid*)&As[BUF][seg0 * 256],       16, 0, 0);                    \
        __builtin_amdgcn_global_load_lds((gvoid*)(aS1 + o_),                  \
            (lvoid*)&As[BUF][seg0 * 256 + 256], 16, 0, 0);                    \
        __builtin_amdgcn_global_load_lds((gvoid*)(bS0 + o_),                  \
            (lvoid*)&Bs[BUF][seg0 * 256],       16, 0, 0);                    \
        __builtin_amdgcn_global_load_lds((gvoid*)(bS1 + o_),                  \
            (lvoid*)&Bs[BUF][seg0 * 256 + 256], 16, 0, 0);                    \
    } while (0)

    const int rowA0 = wm + (lane & 31);
    const int rowA1 = rowA0 + 32;
    const int rowB0 = wn + (lane & 31);
    const int rowB1 = rowB0 + 32;
    const int kbase = (lane >> 5) * 32;   // byte offset of lane's k-half

    f32x16 acc00 = {0.f}, acc01 = {0.f}, acc10 = {0.f}, acc11 = {0.f};

#define COMPUTE(BUF)                                                          \
    do {                                                                      \
        const float* as_ = As[BUF];                                           \
        const float* bs_ = Bs[BUF];                                           \
        _Pragma("unroll")                                                     \
        for (int ks = 0; ks < 2; ++ks) {                                      \
            const int sb = ks * 64 + kbase;                                   \
            s16x8 a0 = rd_frag(as_, rowA0, sb);                               \
            s16x8 b0 = rd_frag(bs_, rowB0, sb);                               \
            s16x8 a1 = rd_frag(as_, rowA1, sb);                               \
            s16x8 b1 = rd_frag(bs_, rowB1, sb);                               \
            acc00 = __builtin_amdgcn_mfma_f32_32x32x16_bf16(a0, b0, acc00, 0, 0, 0); \
            acc01 = __builtin_amdgcn_mfma_f32_32x32x16_bf16(a0, b1, acc01, 0, 0, 0); \
            acc10 = __builtin_amdgcn_mfma_f32_32x32x16_bf16(a1, b0, acc10, 0, 0, 0); \
            acc11 = __builtin_amdgcn_mfma_f32_32x32x16_bf16(a1, b1, acc11, 0, 0, 0); \
        }                                                                     \
    } while (0)

    // prologue: tiles 0 and 1 in flight (8 outstanding vmem ops per wave)
    ISSUE(0, 0);
    ISSUE(1, 1);

    for (int i = 0; i + 2 < NS; ++i) {
        // wait own 4 oldest (tile i) BEFORE barrier -> after barrier all
        // waves' tile-i loads have landed. tile i+1 stays in flight.
        asm volatile("s_waitcnt vmcnt(4)\n\ts_barrier" ::: "memory");
        COMPUTE(i & 1);
        // drain own ds_reads, then barrier: nobody overwrites buf while read
        asm volatile("s_waitcnt lgkmcnt(0)\n\ts_barrier" ::: "memory");
        ISSUE(i + 2, i & 1);
    }
    // peeled tail: i = NS-2 (no new issue), then i = NS-1 (full drain)
    asm volatile("s_waitcnt vmcnt(4)\n\ts_barrier" ::: "memory");
    COMPUTE((NS - 2) & 1);
    asm volatile("s_waitcnt vmcnt(0)\n\ts_barrier" ::: "memory");
    COMPUTE((NS - 1) & 1);

#undef ISSUE
#undef COMPUTE

    // epilogue: C/D map col=lane&31, row=(reg&3)+8*(reg>>2)+4*(lane>>5)
    float* outp = partials + (size_t)blockIdx.x * (NROW * NROW);
    const int ccol = wn + (lane & 31);
    const int rb   = wm + (lane >> 5) * 4;
#pragma unroll
    for (int r = 0; r < 16; ++r) {
        const int crow = rb + (r & 3) + 8 * (r >> 2);
        outp[(size_t)crow * NROW + ccol]             = acc00[r];
        outp[(size_t)crow * NROW + ccol + 32]        = acc01[r];
        outp[(size_t)(crow + 32) * NROW + ccol]      = acc10[r];
        outp[(size_t)(crow + 32) * NROW + ccol + 32] = acc11[r];
    }
}

// Stage 2: reduce partials over split; per-row masked exp, rowsum, pos, rowloss; store E.
__global__ __launch_bounds__(NROW) void reduce_loss_rows(
    const float* __restrict__ partials, const int* __restrict__ idx,
    float* __restrict__ E, float* __restrict__ rowloss, float* __restrict__ posbuf,
    int split)
{
    const int b = blockIdx.x;   // row
    const int t = threadIdx.x;  // col
    const float* p = partials + b * NROW + t;
    float sum = 0.f;
#pragma unroll 8
    for (int s = 0; s < split; ++s)
        sum += p[(size_t)s * (NROW * NROW)];

    const float logit = sum * TEMP;
    const bool  mask  = (idx[b] != idx[t]) || (b == t);
    const float e     = mask ? expf(logit) : 0.0f;
    E[b * NROW + t] = e;

    __shared__ float red[NROW];
    __shared__ float posv;
    if (t == b) posv = logit;
    red[t] = e;
    __syncthreads();
#pragma unroll
    for (int s = NROW / 2; s > 0; s >>= 1) {
        if (t < s) red[t] += red[t + s];
        __syncthreads();
    }
    if (t == 0) {
        posbuf[b]  = posv;
        rowloss[b] = logf(red[0]) - posv;
    }
}

// Stage 3: column sums of E, column losses, final mean.
__global__ __launch_bounds__(NROW) void finalize_loss(
    const float* __restrict__ E, const float* __restrict__ rowloss,
    const float* __restrict__ posbuf, float* __restrict__ out)
{
    const int t = threadIdx.x;
    float csum = 0.f;
#pragma unroll 8
    for (int i = 0; i < NROW; ++i)
        csum += E[i * NROW + t];
    const float closs = logf(csum) - posbuf[t];
    const float rl    = rowloss[t];

    __shared__ float redc[NROW];
    __shared__ float redr[NROW];
    redc[t] = closs;
    redr[t] = rl;
    __syncthreads();
#pragma unroll
    for (int s = NROW / 2; s > 0; s >>= 1) {
        if (t < s) { redc[t] += redc[t + s]; redr[t] += redr[t + s]; }
        __syncthreads();
    }
    if (t == 0)
        out[0] = 0.5f * (redc[0] + redr[0]) * (1.0f / (float)NROW);
}

extern "C" void kernel_launch(void* const* d_in, const int* in_sizes, int n_in,
                              void* d_out, int out_size, void* d_ws, size_t ws_size,
                              hipStream_t stream)
{
    (void)in_sizes; (void)n_in; (void)out_size;
    const float* A   = (const float*)d_in[0];
    const float* Bm  = (const float*)d_in[1];
    const int*   idx = (const int*)d_in[2];
    float*       out = (float*)d_out;

    // adaptive split-K based on workspace size (partials: split * 256KB)
    int split = 256;
    const size_t extra = (size_t)(NROW * NROW + 2 * NROW) * sizeof(float);
    while (split > 8 &&
           (size_t)split * NROW * NROW * sizeof(float) + extra > ws_size)
        split >>= 1;
    const int KC = K_DIM / split;

    float* partials = (float*)d_ws;
    float* E        = partials + (size_t)split * NROW * NROW;
    float* rowloss  = E + NROW * NROW;
    float* posbuf   = rowloss + NROW;

    gemm_fullc<<<split, TPB, 0, stream>>>(A, Bm, partials, KC);
    reduce_loss_rows<<<NROW, NROW, 0, stream>>>(partials, idx, E, rowloss, posbuf, split);
    finalize_loss<<<1, NROW, 0, stream>>>(E, rowloss, posbuf, out);
}